// Round 1
// baseline (374.162 us; speedup 1.0000x reference)
//
#include <hip/hip_runtime.h>
#include <math.h>

#define B_      16
#define M_      32
#define A_TOT   21824
#define NROWS   (B_*A_TOT)      // 349184
#define NUM_FG_ 80
#define EPSF    1e-6f
#define NB0     1364            // NROWS/256 exactly
#define NB1     4096
#define NCAND   45

__device__ __forceinline__ float waveReduceSum(float v) {
    for (int o = 32; o > 0; o >>= 1) v += __shfl_down(v, o, 64);
    return v;
}
__device__ __forceinline__ unsigned long long waveReduceMinU64(unsigned long long v) {
    for (int o = 32; o > 0; o >>= 1) {
        unsigned long long other = __shfl_down(v, o, 64);
        v = other < v ? other : v;
    }
    return v;
}

// ---------------- zero the per-(b,anchor) best-key table ----------------
__global__ __launch_bounds__(256) void k_init(unsigned long long* __restrict__ keys) {
    int t = blockIdx.x * 256 + threadIdx.x;
    if (t < NROWS) keys[t] = 0ULL;
}

// ---------------- ATSS assignment: one wave per (b, gt) ----------------
__global__ __launch_bounds__(64) void k_assign(
    const float* __restrict__ anchors,
    const float* __restrict__ gtb,
    unsigned long long* __restrict__ keys)
{
    const int lvl_base[5] = {0, 16384, 20480, 21504, 21760};
    const int lvl_n[5]    = {16384, 4096, 1024, 256, 64};
    int bg = blockIdx.x;
    int b = bg >> 5, g = bg & 31;
    const float* gt = gtb + (b * M_ + g) * 5;
    float g0 = gt[0], g1 = gt[1], g2 = gt[2], g3 = gt[3];
    bool valid = gt[4] > 0.f;
    float gcx = (g0 + g2) * 0.5f, gcy = (g1 + g3) * 0.5f;
    int lane = threadIdx.x;
    __shared__ int cand[NCAND];

    for (int l = 0; l < 5; ++l) {
        unsigned long long t9[9];
#pragma unroll
        for (int j = 0; j < 9; ++j) t9[j] = ~0ULL;
        int n = lvl_n[l], base = lvl_base[l];
        for (int i = lane; i < n; i += 64) {
            int a = base + i;
            float4 an = ((const float4*)anchors)[a];
            float acx = (an.x + an.z) * 0.5f, acy = (an.y + an.w) * 0.5f;
            float dx = acx - gcx, dy = acy - gcy;
            float dist = sqrtf(dx * dx + dy * dy);
            unsigned long long key =
                ((unsigned long long)__float_as_uint(dist) << 32) | (unsigned)a;
            if (key < t9[8]) {          // sorted insert, static indices only
                t9[8] = key;
#pragma unroll
                for (int j = 8; j > 0; --j) {
                    unsigned long long lo = t9[j] < t9[j-1] ? t9[j] : t9[j-1];
                    unsigned long long hi = t9[j] < t9[j-1] ? t9[j-1] : t9[j];
                    t9[j-1] = lo; t9[j] = hi;
                }
            }
        }
        // merge 64 sorted lists: 9 rounds of wave-min (keys unique -> one winner)
        for (int j = 0; j < 9; ++j) {
            unsigned long long m = waveReduceMinU64(t9[0]);
            m = __shfl(m, 0, 64);
            if (t9[0] == m) {
#pragma unroll
                for (int q = 0; q < 8; ++q) t9[q] = t9[q+1];
                t9[8] = ~0ULL;
            }
            if (lane == 0) cand[l * 9 + j] = (int)(m & 0xffffffffu);
        }
    }
    __syncthreads();

    float iou = 0.f; bool inside = false; int a = 0;
    if (lane < NCAND) {
        a = cand[lane];
        float4 an = ((const float4*)anchors)[a];
        float tlx = fmaxf(an.x, g0), tly = fmaxf(an.y, g1);
        float brx = fminf(an.z, g2), bry = fminf(an.w, g3);
        float w = fmaxf(brx - tlx, 0.f), h = fmaxf(bry - tly, 0.f);
        float inter = w * h;
        float aa = (an.z - an.x) * (an.w - an.y);
        float ag = (g2 - g0) * (g3 - g1);
        iou = inter / fmaxf(aa + ag - inter, EPSF);
        float ccx = (an.x + an.z) * 0.5f, ccy = (an.y + an.w) * 0.5f;
        float li = ccx - g0, ti = ccy - g1, ri = g2 - ccx, bi = g3 - ccy;
        inside = fminf(fminf(li, ri), fminf(ti, bi)) > 0.01f;
    }
    // two-pass mean/std (ddof=1), matching jnp.std
    float s = waveReduceSum(lane < NCAND ? iou : 0.f);
    float mean = __shfl(s, 0, 64) * (1.f / 45.f);
    float d = (lane < NCAND) ? (iou - mean) : 0.f;
    float ss = waveReduceSum(d * d);
    float thr = mean + sqrtf(__shfl(ss, 0, 64) * (1.f / 44.f));
    if (lane < NCAND && valid && inside && iou >= thr) {
        unsigned long long key =
            ((unsigned long long)__float_as_uint(iou) << 32) | (unsigned)(31 - g);
        atomicMax(&keys[(size_t)b * A_TOT + a], key);
    }
}

// ---------------- per-row losses: reg (giou), ctn (bce), jsd ----------------
__global__ __launch_bounds__(256) void k_row(
    const float* __restrict__ pred_reg,
    const float* __restrict__ pred_ctn,
    const float* __restrict__ anchors,
    const float* __restrict__ gtb,
    const unsigned long long* __restrict__ keys,
    double* __restrict__ part0)
{
    int t = blockIdx.x * 256 + threadIdx.x;
    float reg = 0.f, ctn = 0.f, jsd = 0.f, fgc = 0.f;
    if (t < NROWS) {
        unsigned long long key = keys[t];
        if (key) {
            fgc = 1.f;
            int b = t / A_TOT;
            int a = t - b * A_TOT;
            int g = 31 - (int)(key & 0xffffffffu);
            const float* gt = gtb + (b * M_ + g) * 5;
            float g0 = gt[0], g1 = gt[1], g2 = gt[2], g3 = gt[3];
            float4 an = ((const float4*)anchors)[a];
            float aw = an.z - an.x, ah = an.w - an.y;
            float ax = (an.x + an.z) * 0.5f, ay = (an.y + an.w) * 0.5f;
            // encode(gt, anchor)
            float gw = fmaxf(g2 - g0, EPSF), gh = fmaxf(g3 - g1, EPSF);
            float gx = (g0 + g2) * 0.5f, gy = (g1 + g3) * 0.5f;
            float e0 = (gx - ax) / aw, e1 = (gy - ay) / ah;
            float e2 = __logf(gw / aw), e3 = __logf(gh / ah);
            // decode(target)
            float tw = __expf(fminf(fmaxf(e2, -4.f), 4.f)) * aw;
            float th = __expf(fminf(fmaxf(e3, -4.f), 4.f)) * ah;
            float tcx = ax + e0 * aw, tcy = ay + e1 * ah;
            float tb0 = tcx - 0.5f * tw, tb1 = tcy - 0.5f * th;
            float tb2 = tcx + 0.5f * tw, tb3 = tcy + 0.5f * th;
            // decode(pred)
            const float* pr = pred_reg + (size_t)t * 8;
            float p0 = pr[0], p1 = pr[1], p2 = pr[2], p3 = pr[3];
            float l0 = pr[4], l1 = pr[5], l2 = pr[6], l3 = pr[7];
            float pw = __expf(fminf(fmaxf(p2, -4.f), 4.f)) * aw;
            float ph = __expf(fminf(fmaxf(p3, -4.f), 4.f)) * ah;
            float pcx = ax + p0 * aw, pcy = ay + p1 * ah;
            float pb0 = pcx - 0.5f * pw, pb1 = pcy - 0.5f * ph;
            float pb2 = pcx + 0.5f * pw, pb3 = pcy + 0.5f * ph;
            // giou(pbox, tbox)
            float tlx = fmaxf(pb0, tb0), tly = fmaxf(pb1, tb1);
            float brx = fminf(pb2, tb2), bry = fminf(pb3, tb3);
            float iw = fmaxf(brx - tlx, 0.f), ih = fmaxf(bry - tly, 0.f);
            float inter = iw * ih;
            float a1 = (pb2 - pb0) * (pb3 - pb1);
            float a2 = (tb2 - tb0) * (tb3 - tb1);
            float uni = fmaxf(a1 + a2 - inter, EPSF);
            float iou = inter / uni;
            float ex0 = fminf(pb0, tb0), ey0 = fminf(pb1, tb1);
            float ex1 = fmaxf(pb2, tb2), ey1 = fmaxf(pb3, tb3);
            float ew = fmaxf(ex1 - ex0, 0.f), eh = fmaxf(ey1 - ey0, 0.f);
            float enc = fmaxf(ew * eh, EPSF);
            reg = 1.f - (iou - (enc - uni) / enc);
            // centerness target from decoded tbox
            float cl = fmaxf(ax - tb0, EPSF), cr = fmaxf(tb2 - ax, EPSF);
            float ct = fmaxf(ay - tb1, EPSF), cb = fmaxf(tb3 - ay, EPSF);
            float ratio = fminf(cl, cr) / fmaxf(cl, cr) * (fminf(ct, cb) / fmaxf(ct, cb));
            float cstar = sqrtf(fminf(fmaxf(ratio, EPSF), 1.f));
            float z = pred_ctn[t];
            ctn = fmaxf(z, 0.f) - z * cstar + log1pf(__expf(-fabsf(z)));
            // jsd (on encoded target)
            float mu[4] = {p0, p1, p2, p3}, ls[4] = {l0, l1, l2, l3};
            float ee[4] = {e0, e1, e2, e3};
            float ksum = 0.f;
#pragma unroll
            for (int i = 0; i < 4; ++i) {
                float var = __expf(2.f * ls[i]);
                float d2 = (mu[i] - ee[i]) * (mu[i] - ee[i]);
                float kl_pt = -ls[i] + 0.5f * (var + d2) - 0.5f;
                float kl_tp = ls[i] + (1.f + d2) / (2.f * var) - 0.5f;
                ksum += kl_pt + kl_tp;
            }
            jsd = 0.5f * ksum;
        }
    }
    // block reduce 4 values -> one partial per block (no atomics)
    float vr = waveReduceSum(reg), vc = waveReduceSum(ctn);
    float vj = waveReduceSum(jsd), vf = waveReduceSum(fgc);
    __shared__ float sbuf[4][4];
    int wid = threadIdx.x >> 6, lid = threadIdx.x & 63;
    if (lid == 0) { sbuf[wid][0] = vr; sbuf[wid][1] = vc; sbuf[wid][2] = vj; sbuf[wid][3] = vf; }
    __syncthreads();
    if (threadIdx.x == 0) {
        double r = 0, c = 0, j = 0, f = 0;
        for (int w = 0; w < 4; ++w) { r += sbuf[w][0]; c += sbuf[w][1]; j += sbuf[w][2]; f += sbuf[w][3]; }
        part0[blockIdx.x * 4 + 0] = r; part0[blockIdx.x * 4 + 1] = c;
        part0[blockIdx.x * 4 + 2] = j; part0[blockIdx.x * 4 + 3] = f;
    }
}

// ---------------- focal classification loss: streams pred_cls ----------------
__global__ __launch_bounds__(256) void k_cls(
    const float4* __restrict__ cls4,
    const float* __restrict__ gtb,
    const unsigned long long* __restrict__ keys,
    double* __restrict__ part1)
{
    const int total4 = NROWS * (NUM_FG_ / 4);   // 6,983,680 float4s; 80%4==0 so no row-crossing
    float acc = 0.f;
    for (int i = blockIdx.x * 256 + threadIdx.x; i < total4; i += gridDim.x * 256) {
        float4 v = cls4[i];
        int row = i / 20;
        int c0 = (i - row * 20) * 4;
        unsigned long long key = keys[row];
        int tgt = -1;
        if (key) {
            int b = row / A_TOT;
            int g = 31 - (int)(key & 0xffffffffu);
            tgt = (int)gtb[(b * M_ + g) * 5 + 4] - 1;
        }
        float xs[4] = {v.x, v.y, v.z, v.w};
#pragma unroll
        for (int j = 0; j < 4; ++j) {
            float x = xs[j];
            float p = 1.f / (1.f + __expf(-x));
            float loss;
            if (c0 + j == tgt)
                loss = -0.25f * (1.f - p) * (1.f - p) * __logf(fmaxf(p, 1e-12f));
            else
                loss = -0.75f * p * p * __logf(fmaxf(1.f - p, 1e-12f));
            acc += loss;
        }
    }
    acc = waveReduceSum(acc);
    __shared__ float sb[4];
    int wid = threadIdx.x >> 6, lid = threadIdx.x & 63;
    if (lid == 0) sb[wid] = acc;
    __syncthreads();
    if (threadIdx.x == 0)
        part1[blockIdx.x] = (double)sb[0] + sb[1] + sb[2] + sb[3];
}

// ---------------- final reduction + normalization ----------------
__global__ __launch_bounds__(256) void k_final(
    const double* __restrict__ part0,
    const double* __restrict__ part1,
    float* __restrict__ out)
{
    double cls = 0, reg = 0, ctn = 0, jsd = 0, fgc = 0;
    for (int i = threadIdx.x; i < NB1; i += 256) cls += part1[i];
    for (int i = threadIdx.x; i < NB0; i += 256) {
        reg += part0[i * 4 + 0]; ctn += part0[i * 4 + 1];
        jsd += part0[i * 4 + 2]; fgc += part0[i * 4 + 3];
    }
    for (int o = 32; o > 0; o >>= 1) {
        cls += __shfl_down(cls, o, 64); reg += __shfl_down(reg, o, 64);
        ctn += __shfl_down(ctn, o, 64); jsd += __shfl_down(jsd, o, 64);
        fgc += __shfl_down(fgc, o, 64);
    }
    __shared__ double sb[5][4];
    int wid = threadIdx.x >> 6, lid = threadIdx.x & 63;
    if (lid == 0) { sb[0][wid] = cls; sb[1][wid] = reg; sb[2][wid] = ctn; sb[3][wid] = jsd; sb[4][wid] = fgc; }
    __syncthreads();
    if (threadIdx.x == 0) {
        double C = sb[0][0] + sb[0][1] + sb[0][2] + sb[0][3];
        double R = sb[1][0] + sb[1][1] + sb[1][2] + sb[1][3];
        double T = sb[2][0] + sb[2][1] + sb[2][2] + sb[2][3];
        double J = sb[3][0] + sb[3][1] + sb[3][2] + sb[3][3];
        double F = sb[4][0] + sb[4][1] + sb[4][2] + sb[4][3];
        double ln = 0.9 * 100.0 + 0.1 * fmax(F, 1.0);
        out[0] = (float)(C / ln);
        out[1] = (float)(R / ln);
        out[2] = (float)(T / ln);
        out[3] = (float)(0.1 * J / ln);   // JS_W applied here
    }
}

extern "C" void kernel_launch(void* const* d_in, const int* in_sizes, int n_in,
                              void* d_out, int out_size, void* d_ws, size_t ws_size,
                              hipStream_t stream) {
    (void)in_sizes; (void)n_in; (void)out_size; (void)ws_size;
    const float* pred_cls = (const float*)d_in[0];
    const float* pred_reg = (const float*)d_in[1];
    const float* pred_ctn = (const float*)d_in[2];
    const float* anchors  = (const float*)d_in[3];
    const float* gtb      = (const float*)d_in[4];
    // im_info (d_in[5]) unused

    unsigned long long* keys = (unsigned long long*)d_ws;          // NROWS * 8 B
    double* part0 = (double*)((char*)d_ws + (size_t)NROWS * 8);    // NB0 * 4 doubles
    double* part1 = part0 + (size_t)NB0 * 4;                       // NB1 doubles

    k_init  <<<NB0, 256, 0, stream>>>(keys);
    k_assign<<<B_ * M_, 64, 0, stream>>>(anchors, gtb, keys);
    k_row   <<<NB0, 256, 0, stream>>>(pred_reg, pred_ctn, anchors, gtb, keys, part0);
    k_cls   <<<NB1, 256, 0, stream>>>((const float4*)pred_cls, gtb, keys, part1);
    k_final <<<1, 256, 0, stream>>>(part0, part1, (float*)d_out);
}

// Round 2
// 210.113 us; speedup vs baseline: 1.7808x; 1.7808x over previous
//
#include <hip/hip_runtime.h>
#include <math.h>

#define B_      16
#define M_      32
#define A_TOT   21824
#define NROWS   (B_*A_TOT)      // 349184
#define NUM_FG_ 80
#define EPSF    1e-6f
#define NB0     1364            // NROWS/256 exactly
#define NB1     4096
#define NCAND   45

__device__ __forceinline__ float waveReduceSum(float v) {
    for (int o = 32; o > 0; o >>= 1) v += __shfl_down(v, o, 64);
    return v;
}
__device__ __forceinline__ unsigned long long waveReduceMinU64(unsigned long long v) {
    for (int o = 32; o > 0; o >>= 1) {
        unsigned long long other = __shfl_down(v, o, 64);
        v = other < v ? other : v;
    }
    return v;
}

// ---------------- ATSS assignment: one wave per (b, gt) ----------------
// Top-9 nearest anchors per level found analytically: anchor centers are a
// regular f x f grid (pitch s). The 9 nearest grid points to a query inside
// the grid span always lie in a 7x7 window around the nearest cell (worst
// case 9th-nearest = 3.54*s at a corner; anything outside the window is
// >= 6.5*s away -> no membership/tie ambiguity). 49 candidates/level.
__global__ __launch_bounds__(64) void k_assign(
    const float* __restrict__ anchors,
    const float* __restrict__ gtb,
    unsigned long long* __restrict__ keys)
{
    const int   lvl_base[5] = {0, 16384, 20480, 21504, 21760};
    const int   lvl_f[5]    = {128, 64, 32, 16, 8};
    const float lvl_s[5]    = {8.f, 16.f, 32.f, 64.f, 128.f};
    int bg = blockIdx.x;
    int b = bg >> 5, g = bg & 31;
    const float* gt = gtb + (b * M_ + g) * 5;
    float g0 = gt[0], g1 = gt[1], g2 = gt[2], g3 = gt[3];
    bool valid = gt[4] > 0.f;
    float gcx = (g0 + g2) * 0.5f, gcy = (g1 + g3) * 0.5f;
    int lane = threadIdx.x;
    __shared__ int cand[NCAND];

    for (int l = 0; l < 5; ++l) {
        int f = lvl_f[l], base = lvl_base[l];
        float s = lvl_s[l];
        int ixn = (int)floorf(gcx / s); ixn = min(max(ixn, 0), f - 1);
        int iyn = (int)floorf(gcy / s); iyn = min(max(iyn, 0), f - 1);
        int ix0 = min(max(ixn - 3, 0), f - 7);
        int iy0 = min(max(iyn - 3, 0), f - 7);
        unsigned long long key = ~0ULL;
        if (lane < 49) {
            int ix = ix0 + lane % 7, iy = iy0 + lane / 7;
            int a = base + iy * f + ix;   // reference layout: row=y (ij meshgrid), col=x
            float4 an = ((const float4*)anchors)[a];
            float acx = (an.x + an.z) * 0.5f, acy = (an.y + an.w) * 0.5f;
            float dx = acx - gcx, dy = acy - gcy;
            float dist = sqrtf(dx * dx + dy * dy);
            key = ((unsigned long long)__float_as_uint(dist) << 32) | (unsigned)a;
        }
        // 9 rounds of wave-min: keys unique (embed anchor idx) -> one winner/round
        for (int j = 0; j < 9; ++j) {
            unsigned long long m = waveReduceMinU64(key);
            m = __shfl(m, 0, 64);
            if (key == m) key = ~0ULL;
            if (lane == 0) cand[l * 9 + j] = (int)(m & 0xffffffffu);
        }
    }
    __syncthreads();

    float iou = 0.f; bool inside = false; int a = 0;
    if (lane < NCAND) {
        a = cand[lane];
        float4 an = ((const float4*)anchors)[a];
        float tlx = fmaxf(an.x, g0), tly = fmaxf(an.y, g1);
        float brx = fminf(an.z, g2), bry = fminf(an.w, g3);
        float w = fmaxf(brx - tlx, 0.f), h = fmaxf(bry - tly, 0.f);
        float inter = w * h;
        float aa = (an.z - an.x) * (an.w - an.y);
        float ag = (g2 - g0) * (g3 - g1);
        iou = inter / fmaxf(aa + ag - inter, EPSF);
        float ccx = (an.x + an.z) * 0.5f, ccy = (an.y + an.w) * 0.5f;
        float li = ccx - g0, ti = ccy - g1, ri = g2 - ccx, bi = g3 - ccy;
        inside = fminf(fminf(li, ri), fminf(ti, bi)) > 0.01f;
    }
    // two-pass mean/std (ddof=1), matching jnp.std
    float s = waveReduceSum(lane < NCAND ? iou : 0.f);
    float mean = __shfl(s, 0, 64) * (1.f / 45.f);
    float d = (lane < NCAND) ? (iou - mean) : 0.f;
    float ss = waveReduceSum(d * d);
    float thr = mean + sqrtf(__shfl(ss, 0, 64) * (1.f / 44.f));
    if (lane < NCAND && valid && inside && iou >= thr) {
        unsigned long long key =
            ((unsigned long long)__float_as_uint(iou) << 32) | (unsigned)(31 - g);
        atomicMax(&keys[(size_t)b * A_TOT + a], key);
    }
}

// ---------------- per-row losses: reg (giou), ctn (bce), jsd ----------------
__global__ __launch_bounds__(256) void k_row(
    const float* __restrict__ pred_reg,
    const float* __restrict__ pred_ctn,
    const float* __restrict__ anchors,
    const float* __restrict__ gtb,
    const unsigned long long* __restrict__ keys,
    double* __restrict__ part0)
{
    int t = blockIdx.x * 256 + threadIdx.x;
    float reg = 0.f, ctn = 0.f, jsd = 0.f, fgc = 0.f;
    if (t < NROWS) {
        unsigned long long key = keys[t];
        if (key) {
            fgc = 1.f;
            int b = t / A_TOT;
            int a = t - b * A_TOT;
            int g = 31 - (int)(key & 0xffffffffu);
            const float* gt = gtb + (b * M_ + g) * 5;
            float g0 = gt[0], g1 = gt[1], g2 = gt[2], g3 = gt[3];
            float4 an = ((const float4*)anchors)[a];
            float aw = an.z - an.x, ah = an.w - an.y;
            float ax = (an.x + an.z) * 0.5f, ay = (an.y + an.w) * 0.5f;
            // encode(gt, anchor)
            float gw = fmaxf(g2 - g0, EPSF), gh = fmaxf(g3 - g1, EPSF);
            float gx = (g0 + g2) * 0.5f, gy = (g1 + g3) * 0.5f;
            float e0 = (gx - ax) / aw, e1 = (gy - ay) / ah;
            float e2 = __logf(gw / aw), e3 = __logf(gh / ah);
            // decode(target)
            float tw = __expf(fminf(fmaxf(e2, -4.f), 4.f)) * aw;
            float th = __expf(fminf(fmaxf(e3, -4.f), 4.f)) * ah;
            float tcx = ax + e0 * aw, tcy = ay + e1 * ah;
            float tb0 = tcx - 0.5f * tw, tb1 = tcy - 0.5f * th;
            float tb2 = tcx + 0.5f * tw, tb3 = tcy + 0.5f * th;
            // decode(pred)
            const float* pr = pred_reg + (size_t)t * 8;
            float p0 = pr[0], p1 = pr[1], p2 = pr[2], p3 = pr[3];
            float l0 = pr[4], l1 = pr[5], l2 = pr[6], l3 = pr[7];
            float pw = __expf(fminf(fmaxf(p2, -4.f), 4.f)) * aw;
            float ph = __expf(fminf(fmaxf(p3, -4.f), 4.f)) * ah;
            float pcx = ax + p0 * aw, pcy = ay + p1 * ah;
            float pb0 = pcx - 0.5f * pw, pb1 = pcy - 0.5f * ph;
            float pb2 = pcx + 0.5f * pw, pb3 = pcy + 0.5f * ph;
            // giou(pbox, tbox)
            float tlx = fmaxf(pb0, tb0), tly = fmaxf(pb1, tb1);
            float brx = fminf(pb2, tb2), bry = fminf(pb3, tb3);
            float iw = fmaxf(brx - tlx, 0.f), ih = fmaxf(bry - tly, 0.f);
            float inter = iw * ih;
            float a1 = (pb2 - pb0) * (pb3 - pb1);
            float a2 = (tb2 - tb0) * (tb3 - tb1);
            float uni = fmaxf(a1 + a2 - inter, EPSF);
            float iou = inter / uni;
            float ex0 = fminf(pb0, tb0), ey0 = fminf(pb1, tb1);
            float ex1 = fmaxf(pb2, tb2), ey1 = fmaxf(pb3, tb3);
            float ew = fmaxf(ex1 - ex0, 0.f), eh = fmaxf(ey1 - ey0, 0.f);
            float enc = fmaxf(ew * eh, EPSF);
            reg = 1.f - (iou - (enc - uni) / enc);
            // centerness target from decoded tbox
            float cl = fmaxf(ax - tb0, EPSF), cr = fmaxf(tb2 - ax, EPSF);
            float ct = fmaxf(ay - tb1, EPSF), cb = fmaxf(tb3 - ay, EPSF);
            float ratio = fminf(cl, cr) / fmaxf(cl, cr) * (fminf(ct, cb) / fmaxf(ct, cb));
            float cstar = sqrtf(fminf(fmaxf(ratio, EPSF), 1.f));
            float z = pred_ctn[t];
            ctn = fmaxf(z, 0.f) - z * cstar + log1pf(__expf(-fabsf(z)));
            // jsd (on encoded target)
            float mu[4] = {p0, p1, p2, p3}, ls[4] = {l0, l1, l2, l3};
            float ee[4] = {e0, e1, e2, e3};
            float ksum = 0.f;
#pragma unroll
            for (int i = 0; i < 4; ++i) {
                float var = __expf(2.f * ls[i]);
                float d2 = (mu[i] - ee[i]) * (mu[i] - ee[i]);
                float kl_pt = -ls[i] + 0.5f * (var + d2) - 0.5f;
                float kl_tp = ls[i] + (1.f + d2) / (2.f * var) - 0.5f;
                ksum += kl_pt + kl_tp;
            }
            jsd = 0.5f * ksum;
        }
    }
    // block reduce 4 values -> one partial per block (no atomics)
    float vr = waveReduceSum(reg), vc = waveReduceSum(ctn);
    float vj = waveReduceSum(jsd), vf = waveReduceSum(fgc);
    __shared__ float sbuf[4][4];
    int wid = threadIdx.x >> 6, lid = threadIdx.x & 63;
    if (lid == 0) { sbuf[wid][0] = vr; sbuf[wid][1] = vc; sbuf[wid][2] = vj; sbuf[wid][3] = vf; }
    __syncthreads();
    if (threadIdx.x == 0) {
        double r = 0, c = 0, j = 0, f = 0;
        for (int w = 0; w < 4; ++w) { r += sbuf[w][0]; c += sbuf[w][1]; j += sbuf[w][2]; f += sbuf[w][3]; }
        part0[blockIdx.x * 4 + 0] = r; part0[blockIdx.x * 4 + 1] = c;
        part0[blockIdx.x * 4 + 2] = j; part0[blockIdx.x * 4 + 3] = f;
    }
}

// ---------------- focal classification loss: streams pred_cls ----------------
__global__ __launch_bounds__(256) void k_cls(
    const float4* __restrict__ cls4,
    const float* __restrict__ gtb,
    const unsigned long long* __restrict__ keys,
    double* __restrict__ part1)
{
    const int total4 = NROWS * (NUM_FG_ / 4);   // 6,983,680 float4s; 80%4==0 so no row-crossing
    float acc = 0.f;
    for (int i = blockIdx.x * 256 + threadIdx.x; i < total4; i += gridDim.x * 256) {
        float4 v = cls4[i];
        int row = i / 20;
        int c0 = (i - row * 20) * 4;
        unsigned long long key = keys[row];
        int tgt = -1;
        if (key) {
            int b = row / A_TOT;
            int g = 31 - (int)(key & 0xffffffffu);
            tgt = (int)gtb[(b * M_ + g) * 5 + 4] - 1;
        }
        float xs[4] = {v.x, v.y, v.z, v.w};
#pragma unroll
        for (int j = 0; j < 4; ++j) {
            float x = xs[j];
            float p = 1.f / (1.f + __expf(-x));
            float loss;
            if (c0 + j == tgt)
                loss = -0.25f * (1.f - p) * (1.f - p) * __logf(fmaxf(p, 1e-12f));
            else
                loss = -0.75f * p * p * __logf(fmaxf(1.f - p, 1e-12f));
            acc += loss;
        }
    }
    acc = waveReduceSum(acc);
    __shared__ float sb[4];
    int wid = threadIdx.x >> 6, lid = threadIdx.x & 63;
    if (lid == 0) sb[wid] = acc;
    __syncthreads();
    if (threadIdx.x == 0)
        part1[blockIdx.x] = (double)sb[0] + sb[1] + sb[2] + sb[3];
}

// ---------------- final reduction + normalization ----------------
__global__ __launch_bounds__(256) void k_final(
    const double* __restrict__ part0,
    const double* __restrict__ part1,
    float* __restrict__ out)
{
    double cls = 0, reg = 0, ctn = 0, jsd = 0, fgc = 0;
    for (int i = threadIdx.x; i < NB1; i += 256) cls += part1[i];
    for (int i = threadIdx.x; i < NB0; i += 256) {
        reg += part0[i * 4 + 0]; ctn += part0[i * 4 + 1];
        jsd += part0[i * 4 + 2]; fgc += part0[i * 4 + 3];
    }
    for (int o = 32; o > 0; o >>= 1) {
        cls += __shfl_down(cls, o, 64); reg += __shfl_down(reg, o, 64);
        ctn += __shfl_down(ctn, o, 64); jsd += __shfl_down(jsd, o, 64);
        fgc += __shfl_down(fgc, o, 64);
    }
    __shared__ double sb[5][4];
    int wid = threadIdx.x >> 6, lid = threadIdx.x & 63;
    if (lid == 0) { sb[0][wid] = cls; sb[1][wid] = reg; sb[2][wid] = ctn; sb[3][wid] = jsd; sb[4][wid] = fgc; }
    __syncthreads();
    if (threadIdx.x == 0) {
        double C = sb[0][0] + sb[0][1] + sb[0][2] + sb[0][3];
        double R = sb[1][0] + sb[1][1] + sb[1][2] + sb[1][3];
        double T = sb[2][0] + sb[2][1] + sb[2][2] + sb[2][3];
        double J = sb[3][0] + sb[3][1] + sb[3][2] + sb[3][3];
        double F = sb[4][0] + sb[4][1] + sb[4][2] + sb[4][3];
        double ln = 0.9 * 100.0 + 0.1 * fmax(F, 1.0);
        out[0] = (float)(C / ln);
        out[1] = (float)(R / ln);
        out[2] = (float)(T / ln);
        out[3] = (float)(0.1 * J / ln);   // JS_W applied here
    }
}

extern "C" void kernel_launch(void* const* d_in, const int* in_sizes, int n_in,
                              void* d_out, int out_size, void* d_ws, size_t ws_size,
                              hipStream_t stream) {
    (void)in_sizes; (void)n_in; (void)out_size; (void)ws_size;
    const float* pred_cls = (const float*)d_in[0];
    const float* pred_reg = (const float*)d_in[1];
    const float* pred_ctn = (const float*)d_in[2];
    const float* anchors  = (const float*)d_in[3];
    const float* gtb      = (const float*)d_in[4];
    // im_info (d_in[5]) unused

    unsigned long long* keys = (unsigned long long*)d_ws;          // NROWS * 8 B
    double* part0 = (double*)((char*)d_ws + (size_t)NROWS * 8);    // NB0 * 4 doubles
    double* part1 = part0 + (size_t)NB0 * 4;                       // NB1 doubles

    hipMemsetAsync(keys, 0, (size_t)NROWS * 8, stream);            // zero best-key table
    k_assign<<<B_ * M_, 64, 0, stream>>>(anchors, gtb, keys);
    k_row   <<<NB0, 256, 0, stream>>>(pred_reg, pred_ctn, anchors, gtb, keys, part0);
    k_cls   <<<NB1, 256, 0, stream>>>((const float4*)pred_cls, gtb, keys, part1);
    k_final <<<1, 256, 0, stream>>>(part0, part1, (float*)d_out);
}

// Round 3
// 192.147 us; speedup vs baseline: 1.9473x; 1.0935x over previous
//
#include <hip/hip_runtime.h>
#include <math.h>

#define B_      16
#define M_      32
#define A_TOT   21824
#define NROWS   (B_*A_TOT)      // 349184
#define NUM_FG_ 80
#define EPSF    1e-6f
#define NCAND   45
#define NBF     2048            // fused-kernel grid (8 blocks/CU)

__device__ __forceinline__ float waveReduceSum(float v) {
    for (int o = 32; o > 0; o >>= 1) v += __shfl_down(v, o, 64);
    return v;
}

// ---------------- ATSS assignment: one wave per (b, gt) ----------------
// Top-9 nearest per level via analytic 7x7 window (see R1: worst-case 9th
// nearest <= 2.13*s, outside-window >= 3.5*s -> no ambiguity; validated
// absmax==0). Extraction by rank-counting in LDS (no serial shfl chain):
// rank = #keys smaller within the level's 49; rank<9 scatters its anchor
// index to cand[level*9+rank] -- identical order to the old wave-min
// extraction, so the threshold tail below is bit-identical to R2.
__global__ __launch_bounds__(64) void k_assign(
    const float* __restrict__ anchors,
    const float* __restrict__ gtb,
    unsigned long long* __restrict__ keys)
{
    const int   lvl_base[5] = {0, 16384, 20480, 21504, 21760};
    const int   lvl_f[5]    = {128, 64, 32, 16, 8};
    const float lvl_s[5]    = {8.f, 16.f, 32.f, 64.f, 128.f};
    int bg = blockIdx.x;
    int b = bg >> 5, g = bg & 31;
    const float* gt = gtb + (b * M_ + g) * 5;
    float g0 = gt[0], g1 = gt[1], g2 = gt[2], g3 = gt[3];
    bool valid = gt[4] > 0.f;
    float gcx = (g0 + g2) * 0.5f, gcy = (g1 + g3) * 0.5f;
    int lane = threadIdx.x;

    __shared__ unsigned long long kbuf[5 * 49];
    __shared__ int cand[NCAND];

    unsigned long long mykey[4];
    int myanchor[4];
    // phase 1: compute 245 candidate keys (centers analytic & exact in fp32)
#pragma unroll
    for (int q = 0; q < 4; ++q) {
        int cid = lane + 64 * q;
        mykey[q] = ~0ULL;
        if (cid < 245) {
            int l = cid / 49, j = cid - l * 49;
            int f = lvl_f[l];
            float s = lvl_s[l];
            int ixn = (int)floorf(gcx / s); ixn = min(max(ixn, 0), f - 1);
            int iyn = (int)floorf(gcy / s); iyn = min(max(iyn, 0), f - 1);
            int ix0 = min(max(ixn - 3, 0), f - 7);
            int iy0 = min(max(iyn - 3, 0), f - 7);
            int ix = ix0 + j % 7, iy = iy0 + j / 7;
            int a = lvl_base[l] + iy * f + ix;   // row=y (ij meshgrid), col=x
            float acx = ((float)ix + 0.5f) * s;  // == (an.x+an.z)*0.5 bit-exact
            float acy = ((float)iy + 0.5f) * s;
            float dx = acx - gcx, dy = acy - gcy;
            float dist = sqrtf(dx * dx + dy * dy);
            mykey[q] = ((unsigned long long)__float_as_uint(dist) << 32) | (unsigned)a;
            myanchor[q] = a;
            kbuf[cid] = mykey[q];
        }
    }
    __syncthreads();
    // phase 2: rank within level; rank<9 -> scatter anchor idx in rank order
#pragma unroll
    for (int q = 0; q < 4; ++q) {
        int cid = lane + 64 * q;
        if (cid < 245) {
            int l = cid / 49;
            const unsigned long long* kg = &kbuf[l * 49];
            int cnt = 0;
            for (int j = 0; j < 49; ++j) cnt += (kg[j] < mykey[q]);
            if (cnt < 9) cand[l * 9 + cnt] = myanchor[q];
        }
    }
    __syncthreads();

    // threshold tail: identical to the validated R2 kernel
    float iou = 0.f; bool inside = false; int a = 0;
    if (lane < NCAND) {
        a = cand[lane];
        float4 an = ((const float4*)anchors)[a];
        float tlx = fmaxf(an.x, g0), tly = fmaxf(an.y, g1);
        float brx = fminf(an.z, g2), bry = fminf(an.w, g3);
        float w = fmaxf(brx - tlx, 0.f), h = fmaxf(bry - tly, 0.f);
        float inter = w * h;
        float aa = (an.z - an.x) * (an.w - an.y);
        float ag = (g2 - g0) * (g3 - g1);
        iou = inter / fmaxf(aa + ag - inter, EPSF);
        float ccx = (an.x + an.z) * 0.5f, ccy = (an.y + an.w) * 0.5f;
        float li = ccx - g0, ti = ccy - g1, ri = g2 - ccx, bi = g3 - ccy;
        inside = fminf(fminf(li, ri), fminf(ti, bi)) > 0.01f;
    }
    float s = waveReduceSum(lane < NCAND ? iou : 0.f);
    float mean = __shfl(s, 0, 64) * (1.f / 45.f);
    float d = (lane < NCAND) ? (iou - mean) : 0.f;
    float ss = waveReduceSum(d * d);
    float thr = mean + sqrtf(__shfl(ss, 0, 64) * (1.f / 44.f));
    if (lane < NCAND && valid && inside && iou >= thr) {
        unsigned long long key =
            ((unsigned long long)__float_as_uint(iou) << 32) | (unsigned)(31 - g);
        atomicMax(&keys[(size_t)b * A_TOT + a], key);
    }
}

// ------- fused: focal cls sweep + fg-row losses (reg/ctn/jsd/fgcount) -------
__global__ __launch_bounds__(256) void k_fused(
    const float4* __restrict__ cls4,
    const float* __restrict__ pred_reg,
    const float* __restrict__ pred_ctn,
    const float* __restrict__ anchors,
    const float* __restrict__ gtb,
    const unsigned long long* __restrict__ keys,
    double* __restrict__ part)
{
    const int total4 = NROWS * (NUM_FG_ / 4);   // 6,983,680; 80%4==0 -> no row-crossing
    float accC = 0.f, accR = 0.f, accT = 0.f, accJ = 0.f, accF = 0.f;
    for (int i = blockIdx.x * 256 + threadIdx.x; i < total4; i += NBF * 256) {
        float4 v = cls4[i];
        int row = i / 20;
        int c0 = (i - row * 20) * 4;
        unsigned long long key = keys[row];
        int tgt = -1;
        int b = row / A_TOT;
        int g = 0;
        if (key) {
            g = 31 - (int)(key & 0xffffffffu);
            tgt = (int)gtb[(b * M_ + g) * 5 + 4] - 1;
        }
        float xs[4] = {v.x, v.y, v.z, v.w};
#pragma unroll
        for (int j = 0; j < 4; ++j) {
            float x = xs[j];
            float p = 1.f / (1.f + __expf(-x));
            float loss;
            if (c0 + j == tgt)
                loss = -0.25f * (1.f - p) * (1.f - p) * __logf(fmaxf(p, 1e-12f));
            else
                loss = -0.75f * p * p * __logf(fmaxf(1.f - p, 1e-12f));
            accC += loss;
        }
        if (c0 == 0 && key) {   // fg-row losses, once per row (rare: ~0.6% of rows)
            accF += 1.f;
            int aidx = row - b * A_TOT;
            const float* gt = gtb + (b * M_ + g) * 5;
            float g0 = gt[0], g1 = gt[1], g2 = gt[2], g3 = gt[3];
            float4 an = ((const float4*)anchors)[aidx];
            float aw = an.z - an.x, ah = an.w - an.y;
            float ax = (an.x + an.z) * 0.5f, ay = (an.y + an.w) * 0.5f;
            float gw = fmaxf(g2 - g0, EPSF), gh = fmaxf(g3 - g1, EPSF);
            float gx = (g0 + g2) * 0.5f, gy = (g1 + g3) * 0.5f;
            float e0 = (gx - ax) / aw, e1 = (gy - ay) / ah;
            float e2 = __logf(gw / aw), e3 = __logf(gh / ah);
            float tw = __expf(fminf(fmaxf(e2, -4.f), 4.f)) * aw;
            float th = __expf(fminf(fmaxf(e3, -4.f), 4.f)) * ah;
            float tcx = ax + e0 * aw, tcy = ay + e1 * ah;
            float tb0 = tcx - 0.5f * tw, tb1 = tcy - 0.5f * th;
            float tb2 = tcx + 0.5f * tw, tb3 = tcy + 0.5f * th;
            const float* pr = pred_reg + (size_t)row * 8;
            float p0 = pr[0], p1 = pr[1], p2 = pr[2], p3 = pr[3];
            float l0 = pr[4], l1 = pr[5], l2 = pr[6], l3 = pr[7];
            float pw = __expf(fminf(fmaxf(p2, -4.f), 4.f)) * aw;
            float ph = __expf(fminf(fmaxf(p3, -4.f), 4.f)) * ah;
            float pcx = ax + p0 * aw, pcy = ay + p1 * ah;
            float pb0 = pcx - 0.5f * pw, pb1 = pcy - 0.5f * ph;
            float pb2 = pcx + 0.5f * pw, pb3 = pcy + 0.5f * ph;
            float tlx = fmaxf(pb0, tb0), tly = fmaxf(pb1, tb1);
            float brx = fminf(pb2, tb2), bry = fminf(pb3, tb3);
            float iw = fmaxf(brx - tlx, 0.f), ih = fmaxf(bry - tly, 0.f);
            float inter = iw * ih;
            float a1 = (pb2 - pb0) * (pb3 - pb1);
            float a2 = (tb2 - tb0) * (tb3 - tb1);
            float uni = fmaxf(a1 + a2 - inter, EPSF);
            float iou = inter / uni;
            float ex0 = fminf(pb0, tb0), ey0 = fminf(pb1, tb1);
            float ex1 = fmaxf(pb2, tb2), ey1 = fmaxf(pb3, tb3);
            float ew = fmaxf(ex1 - ex0, 0.f), eh = fmaxf(ey1 - ey0, 0.f);
            float enc = fmaxf(ew * eh, EPSF);
            accR += 1.f - (iou - (enc - uni) / enc);
            float cl = fmaxf(ax - tb0, EPSF), cr = fmaxf(tb2 - ax, EPSF);
            float ct = fmaxf(ay - tb1, EPSF), cb = fmaxf(tb3 - ay, EPSF);
            float ratio = fminf(cl, cr) / fmaxf(cl, cr) * (fminf(ct, cb) / fmaxf(ct, cb));
            float cstar = sqrtf(fminf(fmaxf(ratio, EPSF), 1.f));
            float z = pred_ctn[row];
            accT += fmaxf(z, 0.f) - z * cstar + log1pf(__expf(-fabsf(z)));
            float mu[4] = {p0, p1, p2, p3}, ls[4] = {l0, l1, l2, l3};
            float ee[4] = {e0, e1, e2, e3};
            float ksum = 0.f;
#pragma unroll
            for (int k = 0; k < 4; ++k) {
                float var = __expf(2.f * ls[k]);
                float d2 = (mu[k] - ee[k]) * (mu[k] - ee[k]);
                ksum += (-ls[k] + 0.5f * (var + d2) - 0.5f)
                      + ( ls[k] + (1.f + d2) / (2.f * var) - 0.5f);
            }
            accJ += 0.5f * ksum;
        }
    }
    float vC = waveReduceSum(accC), vR = waveReduceSum(accR);
    float vT = waveReduceSum(accT), vJ = waveReduceSum(accJ);
    float vF = waveReduceSum(accF);
    __shared__ float sb[4][5];
    int wid = threadIdx.x >> 6, lid = threadIdx.x & 63;
    if (lid == 0) { sb[wid][0]=vC; sb[wid][1]=vR; sb[wid][2]=vT; sb[wid][3]=vJ; sb[wid][4]=vF; }
    __syncthreads();
    if (threadIdx.x == 0) {
        double C=0,R=0,T=0,J=0,F=0;
        for (int w = 0; w < 4; ++w) { C+=sb[w][0]; R+=sb[w][1]; T+=sb[w][2]; J+=sb[w][3]; F+=sb[w][4]; }
        double* p = part + (size_t)blockIdx.x * 5;
        p[0]=C; p[1]=R; p[2]=T; p[3]=J; p[4]=F;
    }
}

// ---------------- final reduction + normalization ----------------
__global__ __launch_bounds__(256) void k_final(
    const double* __restrict__ part,
    float* __restrict__ out)
{
    double C = 0, R = 0, T = 0, J = 0, F = 0;
    for (int i = threadIdx.x; i < NBF; i += 256) {
        const double* p = part + (size_t)i * 5;
        C += p[0]; R += p[1]; T += p[2]; J += p[3]; F += p[4];
    }
    for (int o = 32; o > 0; o >>= 1) {
        C += __shfl_down(C, o, 64); R += __shfl_down(R, o, 64);
        T += __shfl_down(T, o, 64); J += __shfl_down(J, o, 64);
        F += __shfl_down(F, o, 64);
    }
    __shared__ double sb[5][4];
    int wid = threadIdx.x >> 6, lid = threadIdx.x & 63;
    if (lid == 0) { sb[0][wid]=C; sb[1][wid]=R; sb[2][wid]=T; sb[3][wid]=J; sb[4][wid]=F; }
    __syncthreads();
    if (threadIdx.x == 0) {
        double c = sb[0][0]+sb[0][1]+sb[0][2]+sb[0][3];
        double r = sb[1][0]+sb[1][1]+sb[1][2]+sb[1][3];
        double t = sb[2][0]+sb[2][1]+sb[2][2]+sb[2][3];
        double j = sb[3][0]+sb[3][1]+sb[3][2]+sb[3][3];
        double f = sb[4][0]+sb[4][1]+sb[4][2]+sb[4][3];
        double ln = 0.9 * 100.0 + 0.1 * fmax(f, 1.0);
        out[0] = (float)(c / ln);
        out[1] = (float)(r / ln);
        out[2] = (float)(t / ln);
        out[3] = (float)(0.1 * j / ln);   // JS_W applied here
    }
}

extern "C" void kernel_launch(void* const* d_in, const int* in_sizes, int n_in,
                              void* d_out, int out_size, void* d_ws, size_t ws_size,
                              hipStream_t stream) {
    (void)in_sizes; (void)n_in; (void)out_size; (void)ws_size;
    const float* pred_cls = (const float*)d_in[0];
    const float* pred_reg = (const float*)d_in[1];
    const float* pred_ctn = (const float*)d_in[2];
    const float* anchors  = (const float*)d_in[3];
    const float* gtb      = (const float*)d_in[4];
    // im_info (d_in[5]) unused

    unsigned long long* keys = (unsigned long long*)d_ws;          // NROWS * 8 B
    double* part = (double*)((char*)d_ws + (size_t)NROWS * 8);     // NBF * 5 doubles

    hipMemsetAsync(keys, 0, (size_t)NROWS * 8, stream);            // zero best-key table
    k_assign<<<B_ * M_, 64, 0, stream>>>(anchors, gtb, keys);
    k_fused <<<NBF, 256, 0, stream>>>((const float4*)pred_cls, pred_reg, pred_ctn,
                                      anchors, gtb, keys, part);
    k_final <<<1, 256, 0, stream>>>(part, (float*)d_out);
}